// Round 1
// baseline (815.633 us; speedup 1.0000x reference)
//
#include <hip/hip_runtime.h>
#include <hip/hip_bf16.h>

// Fused masked SDPA: B=64, LQ=LK=1024, D=64, temperature=8.
// One block per (batch, 16 q-rows). 256 threads = 4 waves.
// Pass 1: S = QK^T/8 with key/general masking via bf16 MFMA, scores kept in
//         registers (16 k-tiles x 4 rows per lane), online (m,l) per lane.
// Pass 2: p = exp(s-M)/L (query_mask zeroing), write attn, PV via MFMA.

#define NB   64
#define SLQ  1024
#define SLK  1024
#define DH   64
#define TQ   16
#define TK   64
#define NKT  (SLK / TK)   // 16 k-tiles

typedef __attribute__((ext_vector_type(4))) float          f32x4;
typedef __attribute__((ext_vector_type(8))) __bf16         bf16x8;
typedef __attribute__((ext_vector_type(8))) unsigned short u16x8;
typedef __attribute__((ext_vector_type(4))) unsigned short u16x4;

__device__ __forceinline__ unsigned short f2bf(float f) {
  union { float f; unsigned u; } c; c.f = f;
  unsigned u = c.u;
  u += 0x7fffu + ((u >> 16) & 1u);   // round-to-nearest-even
  return (unsigned short)(u >> 16);
}

__global__ __launch_bounds__(256) void sdpa_fused(
    const float* __restrict__ Q, const float* __restrict__ K,
    const float* __restrict__ V, const int* __restrict__ QM,
    const int* __restrict__ KM, const int* __restrict__ MSK,
    float* __restrict__ OUT_AV, float* __restrict__ OUT_P) {
  const int b    = blockIdx.y;
  const int q0   = blockIdx.x * TQ;
  const int tid  = threadIdx.x;
  const int wave = tid >> 6;
  const int lane = tid & 63;
  const int col  = lane & 15;     // MFMA n / C-col
  const int quad = lane >> 4;     // MFMA k-group / C row-group

  // stride 72 bf16 = 144 B: 16B-aligned rows for ds_read_b128 frag loads
  __shared__ unsigned short Qs[TQ][72];
  __shared__ unsigned short KVs[TK][72];   // K tiles (pass 1), V tiles (pass 2)
  __shared__ unsigned short Ps[TQ][72];    // p staged into A-operand layout
  __shared__ float partM[4][TQ], partL[4][TQ];
  __shared__ float rowM[TQ], rowS[TQ];     // final max, qmask/L

  // ---- stage Q tile: 16x64 fp32 (contiguous) -> bf16 LDS, 1 float4/thread
  {
    f32x4 val = ((const f32x4*)(Q + ((size_t)b * SLQ + q0) * DH))[tid];
    u16x4 h; h[0]=f2bf(val[0]); h[1]=f2bf(val[1]); h[2]=f2bf(val[2]); h[3]=f2bf(val[3]);
    *(u16x4*)&Qs[tid >> 4][(tid & 15) << 2] = h;
  }
  __syncthreads();

  // A-frags for Q: A[m=lane&15][k=quad*8+j], two k-steps of 32
  const bf16x8 aq0 = __builtin_bit_cast(bf16x8, *(const u16x8*)&Qs[col][quad * 8]);
  const bf16x8 aq1 = __builtin_bit_cast(bf16x8, *(const u16x8*)&Qs[col][quad * 8 + 32]);

  float sreg[NKT][4];                        // masked scores, register-resident
  float mloc[4] = {-INFINITY, -INFINITY, -INFINITY, -INFINITY};
  float lloc[4] = {0.f, 0.f, 0.f, 0.f};

  const size_t mbase = ((size_t)b * SLQ + q0) * SLK;
  const float* kb = K + (size_t)b * SLK * DH;
  const float* vb = V + (size_t)b * SLK * DH;

  // =================== Pass 1: S = QK^T/8, masking, online stats ==========
#pragma unroll
  for (int kt = 0; kt < NKT; ++kt) {
    __syncthreads();   // protect KVs from previous iteration's readers
    {
      const f32x4* src = (const f32x4*)(kb + kt * TK * DH);  // 64x64 contiguous
#pragma unroll
      for (int j = 0; j < 4; ++j) {
        int idx = tid + 256 * j;
        f32x4 val = src[idx];
        u16x4 h; h[0]=f2bf(val[0]); h[1]=f2bf(val[1]); h[2]=f2bf(val[2]); h[3]=f2bf(val[3]);
        *(u16x4*)&KVs[idx >> 4][(idx & 15) << 2] = h;
      }
    }
    __syncthreads();

    // wave w computes S-tile rows q0..q0+15, keys kt*64 + w*16 + col
    f32x4 acc = {0.f, 0.f, 0.f, 0.f};
    bf16x8 bk0 = __builtin_bit_cast(bf16x8, *(const u16x8*)&KVs[wave * 16 + col][quad * 8]);
    bf16x8 bk1 = __builtin_bit_cast(bf16x8, *(const u16x8*)&KVs[wave * 16 + col][quad * 8 + 32]);
    acc = __builtin_amdgcn_mfma_f32_16x16x32_bf16(aq0, bk0, acc, 0, 0, 0);
    acc = __builtin_amdgcn_mfma_f32_16x16x32_bf16(aq1, bk1, acc, 0, 0, 0);

    const int gk = kt * TK + wave * 16 + col;
    const int km = KM[b * SLK + gk];
#pragma unroll
    for (int r = 0; r < 4; ++r) {
      const int qq = quad * 4 + r;                 // C-layout: row = quad*4+reg
      const int mv = MSK[mbase + (size_t)qq * SLK + gk];
      float s = (km && mv) ? acc[r] * 0.125f : -INFINITY;
      sreg[kt][r] = s;
      if (s != -INFINITY) {
        if (s > mloc[r]) { lloc[r] = lloc[r] * __expf(mloc[r] - s) + 1.f; mloc[r] = s; }
        else             { lloc[r] += __expf(s - mloc[r]); }
      }
    }
  }

  // ---- combine (m,l) across the 16 lanes holding each row (within quad) ----
#pragma unroll
  for (int r = 0; r < 4; ++r) {
#pragma unroll
    for (int off = 1; off < 16; off <<= 1) {
      float om = __shfl_xor(mloc[r], off, 64);
      float ol = __shfl_xor(lloc[r], off, 64);
      if (om != -INFINITY) {
        if (om > mloc[r]) { lloc[r] = lloc[r] * __expf(mloc[r] - om) + ol; mloc[r] = om; }
        else              { lloc[r] += ol * __expf(om - mloc[r]); }
      }
    }
  }
  if (col == 0) {
#pragma unroll
    for (int r = 0; r < 4; ++r) {
      partM[wave][quad * 4 + r] = mloc[r];
      partL[wave][quad * 4 + r] = lloc[r];
    }
  }
  __syncthreads();
  if (tid < TQ) {   // combine the 4 wave-partials per row
    float M = -INFINITY, L = 0.f;
#pragma unroll
    for (int w = 0; w < 4; ++w) {
      float m_ = partM[w][tid], l_ = partL[w][tid];
      if (m_ != -INFINITY) {
        if (m_ > M) { L = L * __expf(M - m_) + l_; M = m_; }
        else        { L += l_ * __expf(m_ - M); }
      }
    }
    rowM[tid] = M;
    rowS[tid] = QM[b * SLQ + q0 + tid] ? (1.f / L) : 0.f;  // qmask folds to 0
  }
  __syncthreads();

  float Mr[4], Sr[4];
#pragma unroll
  for (int r = 0; r < 4; ++r) { Mr[r] = rowM[quad * 4 + r]; Sr[r] = rowS[quad * 4 + r]; }

  // =================== Pass 2: p = exp(s-M)*S, write attn, O += P V =======
  f32x4 acco = {0.f, 0.f, 0.f, 0.f};
#pragma unroll
  for (int kt = 0; kt < NKT; ++kt) {
    __syncthreads();   // protect KVs/Ps from previous iteration's readers
#pragma unroll
    for (int r = 0; r < 4; ++r) {
      const int qq = quad * 4 + r;
      float p = __expf(sreg[kt][r] - Mr[r]) * Sr[r];
      OUT_P[mbase + (size_t)qq * SLK + kt * TK + wave * 16 + col] = p;
      Ps[qq][wave * 16 + col] = f2bf(p);
    }
    {
      const f32x4* src = (const f32x4*)(vb + kt * TK * DH);
#pragma unroll
      for (int j = 0; j < 4; ++j) {
        int idx = tid + 256 * j;
        f32x4 val = src[idx];
        u16x4 h; h[0]=f2bf(val[0]); h[1]=f2bf(val[1]); h[2]=f2bf(val[2]); h[3]=f2bf(val[3]);
        *(u16x4*)&KVs[idx >> 4][(idx & 15) << 2] = h;
      }
    }
    __syncthreads();

    // A = P[q=lane&15][key=quad*8+j]; B = V[key=quad*8+j][d=wave*16+col]
    bf16x8 ap0 = __builtin_bit_cast(bf16x8, *(const u16x8*)&Ps[col][quad * 8]);
    bf16x8 ap1 = __builtin_bit_cast(bf16x8, *(const u16x8*)&Ps[col][quad * 8 + 32]);
    u16x8 r0, r1;
#pragma unroll
    for (int j = 0; j < 8; ++j) {
      r0[j] = KVs[quad * 8 + j][wave * 16 + col];
      r1[j] = KVs[quad * 8 + j + 32][wave * 16 + col];
    }
    bf16x8 bv0 = __builtin_bit_cast(bf16x8, r0);
    bf16x8 bv1 = __builtin_bit_cast(bf16x8, r1);
    acco = __builtin_amdgcn_mfma_f32_16x16x32_bf16(ap0, bv0, acco, 0, 0, 0);
    acco = __builtin_amdgcn_mfma_f32_16x16x32_bf16(ap1, bv1, acco, 0, 0, 0);
  }

#pragma unroll
  for (int r = 0; r < 4; ++r)
    OUT_AV[((size_t)b * SLQ + q0 + quad * 4 + r) * DH + wave * 16 + col] = acco[r];
}

extern "C" void kernel_launch(void* const* d_in, const int* in_sizes, int n_in,
                              void* d_out, int out_size, void* d_ws, size_t ws_size,
                              hipStream_t stream) {
  const float* q  = (const float*)d_in[0];
  const float* k  = (const float*)d_in[1];
  const float* v  = (const float*)d_in[2];
  const int*   qm = (const int*)d_in[3];
  const int*   km = (const int*)d_in[4];
  const int*   mk = (const int*)d_in[5];
  float* out_av = (float*)d_out;                          // [B,LQ,D]
  float* out_p  = out_av + (size_t)NB * SLQ * DH;         // [B,LQ,LK]
  dim3 grid(SLQ / TQ, NB);
  sdpa_fused<<<grid, dim3(256), 0, stream>>>(q, k, v, qm, km, mk, out_av, out_p);
}

// Round 2
// 631.055 us; speedup vs baseline: 1.2925x; 1.2925x over previous
//
#include <hip/hip_runtime.h>
#include <hip/hip_bf16.h>

// Fused masked SDPA: B=64, LQ=LK=1024, D=64, temperature=8.
// One block per (batch, 16 q-rows), 256 threads = 4 waves, XCD-swizzled grid.
// R2: software-pipelined prefetch (K/V/mask one tile ahead), double-buffered
// LDS (1 barrier per tile instead of 2), V stride 76 (2-way max conflicts),
// branchless online softmax.

#define NB   64
#define SLQ  1024
#define SLK  1024
#define DH   64
#define TQ   16
#define TK   64
#define NKT  16
#define KSTR 72   // K/Q/Ps row stride in u16: 144 B, 16B-aligned for ds_read_b128
#define VSTR 76   // V row stride in u16: 38 dwords -> column reads are 2-way max

typedef __attribute__((ext_vector_type(4))) float          f32x4;
typedef __attribute__((ext_vector_type(8))) __bf16         bf16x8;
typedef __attribute__((ext_vector_type(8))) unsigned short u16x8;
typedef __attribute__((ext_vector_type(4))) unsigned short u16x4;

__device__ __forceinline__ unsigned short f2bf(float f) {
  union { float f; unsigned u; } c; c.f = f;
  unsigned u = c.u;
  u += 0x7fffu + ((u >> 16) & 1u);   // round-to-nearest-even
  return (unsigned short)(u >> 16);
}
__device__ __forceinline__ u16x4 cvt4(f32x4 v) {
  u16x4 h; h[0]=f2bf(v[0]); h[1]=f2bf(v[1]); h[2]=f2bf(v[2]); h[3]=f2bf(v[3]);
  return h;
}

__global__ __launch_bounds__(256, 4) void sdpa_fused(
    const float* __restrict__ Q, const float* __restrict__ K,
    const float* __restrict__ V, const int* __restrict__ QM,
    const int* __restrict__ KM, const int* __restrict__ MSK,
    float* __restrict__ OUT_AV, float* __restrict__ OUT_P) {
  // XCD swizzle: all 64 q-tiles of a batch land on one XCD (g%8 = XCD heuristic)
  const int g    = blockIdx.x;
  const int xcd  = g & 7;
  const int slot = g >> 3;
  const int b    = ((slot >> 6) << 3) | xcd;
  const int q0   = (slot & 63) * TQ;

  const int tid  = threadIdx.x;
  const int wave = tid >> 6;
  const int lane = tid & 63;
  const int col  = lane & 15;     // MFMA C col
  const int quad = lane >> 4;     // MFMA C row-group
  const int gk   = wave * 16 + col; // key-in-tile (pass1) / d-index (pass2)

  __shared__ __align__(16) unsigned short Qs[TQ * KSTR];
  __shared__ __align__(16) unsigned short KV[2][TK * VSTR]; // K@72 / V@76 views
  __shared__ __align__(16) unsigned short Ps[2][TQ * KSTR];
  __shared__ float partM[4][TQ], partL[4][TQ];
  __shared__ float rowM[TQ], rowS[TQ];

  const float* kb = K + (size_t)b * SLK * DH;
  const float* vb = V + (size_t)b * SLK * DH;
  const size_t mbase = ((size_t)b * SLQ + q0) * SLK;

  // ---- stage Q tile (16x64 fp32 -> bf16 LDS) ----
  {
    f32x4 val = ((const f32x4*)(Q + ((size_t)b * SLQ + q0) * DH))[tid];
    *(u16x4*)&Qs[(tid >> 4) * KSTR + ((tid & 15) << 2)] = cvt4(val);
  }

  // ---- prefetch K tile 0 + masks tile 0 into registers ----
  f32x4 kreg[4];
#pragma unroll
  for (int j = 0; j < 4; ++j) kreg[j] = ((const f32x4*)kb)[tid + 256 * j];
  int km_c = KM[b * SLK + gk];
  int msk_c[4];
#pragma unroll
  for (int r = 0; r < 4; ++r)
    msk_c[r] = MSK[mbase + (size_t)(quad * 4 + r) * SLK + gk];

  __syncthreads();   // Qs ready
  const bf16x8 aq0 = __builtin_bit_cast(bf16x8, *(const u16x8*)&Qs[col * KSTR + quad * 8]);
  const bf16x8 aq1 = __builtin_bit_cast(bf16x8, *(const u16x8*)&Qs[col * KSTR + quad * 8 + 32]);

  float sreg[NKT][4];
  float mloc[4] = {-INFINITY, -INFINITY, -INFINITY, -INFINITY};
  float lloc[4] = {0.f, 0.f, 0.f, 0.f};

  // =================== Pass 1: S = QK^T/8, masking, online stats ==========
#pragma unroll
  for (int kt = 0; kt < NKT; ++kt) {
    // stage K tile kt (loaded last iteration) into LDS buffer kt&1
#pragma unroll
    for (int j = 0; j < 4; ++j) {
      int idx = tid + 256 * j;
      *(u16x4*)&KV[kt & 1][(idx >> 4) * KSTR + ((idx & 15) << 2)] = cvt4(kreg[j]);
    }
    __syncthreads();

    // prefetch tile kt+1 (global loads in flight during this tile's compute)
    int km_n = 0, msk_n[4] = {0, 0, 0, 0};
    if (kt < NKT - 1) {
#pragma unroll
      for (int j = 0; j < 4; ++j)
        kreg[j] = ((const f32x4*)kb)[(kt + 1) * (TK * DH / 4) + tid + 256 * j];
      km_n = KM[b * SLK + (kt + 1) * TK + gk];
#pragma unroll
      for (int r = 0; r < 4; ++r)
        msk_n[r] = MSK[mbase + (size_t)(quad * 4 + r) * SLK + (kt + 1) * TK + gk];
    }

    bf16x8 bk0 = __builtin_bit_cast(bf16x8, *(const u16x8*)&KV[kt & 1][gk * KSTR + quad * 8]);
    bf16x8 bk1 = __builtin_bit_cast(bf16x8, *(const u16x8*)&KV[kt & 1][gk * KSTR + quad * 8 + 32]);
    f32x4 acc = {0.f, 0.f, 0.f, 0.f};
    acc = __builtin_amdgcn_mfma_f32_16x16x32_bf16(aq0, bk0, acc, 0, 0, 0);
    acc = __builtin_amdgcn_mfma_f32_16x16x32_bf16(aq1, bk1, acc, 0, 0, 0);

#pragma unroll
    for (int r = 0; r < 4; ++r) {
      float s = (km_c && msk_c[r]) ? acc[r] * 0.125f : -INFINITY;
      sreg[kt][r] = s;
      float mn = fmaxf(mloc[r], s);                 // branchless online update
      if (mn != -INFINITY) {
        lloc[r] = lloc[r] * __expf(mloc[r] - mn) + __expf(s - mn);
        mloc[r] = mn;
      }
    }
    km_c = km_n;
#pragma unroll
    for (int r = 0; r < 4; ++r) msk_c[r] = msk_n[r];
  }

  // ---- prefetch V tile 0 now (lands during the stats reduction) ----
  f32x4 vreg[4];
#pragma unroll
  for (int j = 0; j < 4; ++j) vreg[j] = ((const f32x4*)vb)[tid + 256 * j];

  // ---- combine (m,l): 16-lane butterfly within quad, then across waves ----
#pragma unroll
  for (int r = 0; r < 4; ++r) {
#pragma unroll
    for (int off = 1; off < 16; off <<= 1) {
      float om = __shfl_xor(mloc[r], off, 64);
      float ol = __shfl_xor(lloc[r], off, 64);
      float mn = fmaxf(mloc[r], om);
      if (mn != -INFINITY) {
        lloc[r] = lloc[r] * __expf(mloc[r] - mn) + ol * __expf(om - mn);
        mloc[r] = mn;
      }
    }
  }
  if (col == 0) {
#pragma unroll
    for (int r = 0; r < 4; ++r) {
      partM[wave][quad * 4 + r] = mloc[r];
      partL[wave][quad * 4 + r] = lloc[r];
    }
  }
  __syncthreads();
  if (tid < TQ) {
    float M = -INFINITY, L = 0.f;
#pragma unroll
    for (int w = 0; w < 4; ++w) {
      float m_ = partM[w][tid], l_ = partL[w][tid];
      float mn = fmaxf(M, m_);
      if (mn != -INFINITY) {
        L = L * __expf(M - mn) + l_ * __expf(m_ - mn);
        M = mn;
      }
    }
    rowM[tid] = M;
    rowS[tid] = QM[b * SLQ + q0 + tid] ? (1.f / L) : 0.f;
  }
  __syncthreads();

  float Mr[4], Sr[4];
#pragma unroll
  for (int r = 0; r < 4; ++r) { Mr[r] = rowM[quad * 4 + r]; Sr[r] = rowS[quad * 4 + r]; }

  // =================== Pass 2: p = exp(s-M)*S, write attn, O += P V =======
  f32x4 acco = {0.f, 0.f, 0.f, 0.f};
#pragma unroll
  for (int kt = 0; kt < NKT; ++kt) {
    // stage V tile kt (loaded last iteration) into LDS buffer kt&1, stride 76
#pragma unroll
    for (int j = 0; j < 4; ++j) {
      int idx = tid + 256 * j;
      *(u16x4*)&KV[kt & 1][(idx >> 4) * VSTR + ((idx & 15) << 2)] = cvt4(vreg[j]);
    }
    // compute p, stage into Ps (A-operand layout round trip)
    float p[4];
#pragma unroll
    for (int r = 0; r < 4; ++r) {
      p[r] = __expf(sreg[kt][r] - Mr[r]) * Sr[r];
      Ps[kt & 1][(quad * 4 + r) * KSTR + gk] = f2bf(p[r]);
    }
    __syncthreads();

    // prefetch V tile kt+1
    if (kt < NKT - 1) {
#pragma unroll
      for (int j = 0; j < 4; ++j)
        vreg[j] = ((const f32x4*)vb)[(kt + 1) * (TK * DH / 4) + tid + 256 * j];
    }

    // attn output stores (post-barrier so the barrier drain doesn't wait on them)
#pragma unroll
    for (int r = 0; r < 4; ++r)
      OUT_P[mbase + (size_t)(quad * 4 + r) * SLK + kt * TK + gk] = p[r];

    // A = P[q=col][key=quad*8+j]; B = V[key=quad*8+j][d=gk]
    bf16x8 ap0 = __builtin_bit_cast(bf16x8, *(const u16x8*)&Ps[kt & 1][col * KSTR + quad * 8]);
    bf16x8 ap1 = __builtin_bit_cast(bf16x8, *(const u16x8*)&Ps[kt & 1][col * KSTR + quad * 8 + 32]);
    u16x8 r0, r1;
#pragma unroll
    for (int j = 0; j < 8; ++j) {
      r0[j] = KV[kt & 1][(quad * 8 + j) * VSTR + gk];
      r1[j] = KV[kt & 1][(quad * 8 + j + 32) * VSTR + gk];
    }
    bf16x8 bv0 = __builtin_bit_cast(bf16x8, r0);
    bf16x8 bv1 = __builtin_bit_cast(bf16x8, r1);
    acco = __builtin_amdgcn_mfma_f32_16x16x32_bf16(ap0, bv0, acco, 0, 0, 0);
    acco = __builtin_amdgcn_mfma_f32_16x16x32_bf16(ap1, bv1, acco, 0, 0, 0);
  }

#pragma unroll
  for (int r = 0; r < 4; ++r)
    OUT_AV[((size_t)b * SLQ + q0 + quad * 4 + r) * DH + gk] = acco[r];
}

extern "C" void kernel_launch(void* const* d_in, const int* in_sizes, int n_in,
                              void* d_out, int out_size, void* d_ws, size_t ws_size,
                              hipStream_t stream) {
  const float* q  = (const float*)d_in[0];
  const float* k  = (const float*)d_in[1];
  const float* v  = (const float*)d_in[2];
  const int*   qm = (const int*)d_in[3];
  const int*   km = (const int*)d_in[4];
  const int*   mk = (const int*)d_in[5];
  float* out_av = (float*)d_out;                          // [B,LQ,D]
  float* out_p  = out_av + (size_t)NB * SLQ * DH;         // [B,LQ,LK]
  sdpa_fused<<<dim3(NB * (SLQ / TQ)), dim3(256), 0, stream>>>(q, k, v, qm, km, mk, out_av, out_p);
}

// Round 3
// 591.725 us; speedup vs baseline: 1.3784x; 1.0665x over previous
//
#include <hip/hip_runtime.h>
#include <hip/hip_bf16.h>

// Fused masked SDPA: B=64, LQ=LK=1024, D=64, temperature=8.
// R3: barrier-free main loops. Per-wave PRIVATE LDS slices for K and V
// (each wave only ever needs the K/V rows of its own 16 keys), Q A-frags
// loaded per-lane from global, P->A transpose via private LDS, pass 2 in
// 2-tile steps (K=32 MFMA over each wave's 32 private keys), final O
// cross-wave reduction once at the end. 3 barriers/block instead of 32.

#define NB   64
#define SLQ  1024
#define SLK  1024
#define DH   64
#define TQ   16
#define TK   64
#define NKT  16
#define KSTR 80   // K slice row stride (u16): 160B, 16B-aligned for b128
#define VSTR 76   // V slice row stride (u16): 152B -> column reads 2-way max
#define PSTR 40   // P slice row stride (u16): 80B, 16B-aligned for b128

typedef __attribute__((ext_vector_type(4))) float          f32x4;
typedef __attribute__((ext_vector_type(8))) __bf16         bf16x8;
typedef __attribute__((ext_vector_type(8))) unsigned short u16x8;
typedef __attribute__((ext_vector_type(4))) unsigned short u16x4;

static __device__ __forceinline__ unsigned short f2bf(float f) {
  union { float f; unsigned u; } c; c.f = f;
  unsigned u = c.u;
  u += 0x7fffu + ((u >> 16) & 1u);   // round-to-nearest-even
  return (unsigned short)(u >> 16);
}
static __device__ __forceinline__ u16x4 cvt4(f32x4 v) {
  u16x4 h; h[0]=f2bf(v[0]); h[1]=f2bf(v[1]); h[2]=f2bf(v[2]); h[3]=f2bf(v[3]);
  return h;
}

__global__ __launch_bounds__(256, 3) void sdpa_fused(
    const float* __restrict__ Q, const float* __restrict__ K,
    const float* __restrict__ V, const int* __restrict__ QM,
    const int* __restrict__ KM, const int* __restrict__ MSK,
    float* __restrict__ OUT_AV, float* __restrict__ OUT_P) {
  // XCD swizzle: co-schedule same-batch blocks on one XCD for K/V L2 reuse
  const int g    = blockIdx.x;
  const int slot = g >> 3;
  const int b    = ((slot >> 6) << 3) | (g & 7);
  const int q0   = (slot & 63) * TQ;

  const int tid  = threadIdx.x;
  const int wave = tid >> 6;
  const int lane = tid & 63;
  const int col  = lane & 15;
  const int quad = lane >> 4;
  const int lrow = lane >> 4;        // staging row subgroup
  const int lc4  = (lane & 15) * 4;  // staging column (x4 elements)

  // LDS: region0 [0,19456): per-wave union of K slice (2560 B @ w*2560),
  //      V slice (4864 B @ w*4864), O partial (4096 B @ w*4864, aliases V).
  //      region1 [19456,24576): per-wave P slice (1280 B).
  //      region2 [24576,25216): softmax stats.
  __shared__ __align__(16) unsigned char RAW[25216];
  unsigned short* Kw = (unsigned short*)RAW + wave * (16 * KSTR);
  unsigned short* Vw = (unsigned short*)RAW + wave * (32 * VSTR);
  float*          Ow = (float*)(RAW + wave * (32 * VSTR * 2));
  unsigned short* Pw = (unsigned short*)(RAW + 19456) + wave * (16 * PSTR);
  float* partM = (float*)(RAW + 24576);
  float* partL = partM + 64;
  float* rowM  = partL + 64;
  float* rowS  = rowM + 16;

  const f32x4* kb4 = (const f32x4*)(K + (size_t)b * SLK * DH);
  const f32x4* vb4 = (const f32x4*)(V + (size_t)b * SLK * DH);
  const size_t mbase = ((size_t)b * SLQ + q0) * SLK;

  // ---- Q A-frags straight from global: lane needs Q[q0+col][quad*8+j(+32)]
  const float* qp = Q + ((size_t)b * SLQ + q0 + col) * DH + quad * 8;
  bf16x8 aq0, aq1;
  {
    u16x4 a = cvt4(*(const f32x4*)qp),        c = cvt4(*(const f32x4*)(qp + 4));
    u16x4 d = cvt4(*(const f32x4*)(qp + 32)), e = cvt4(*(const f32x4*)(qp + 36));
    u16x8 h0, h1;
#pragma unroll
    for (int j = 0; j < 4; ++j) { h0[j]=a[j]; h0[j+4]=c[j]; h1[j]=d[j]; h1[j+4]=e[j]; }
    aq0 = __builtin_bit_cast(bf16x8, h0);
    aq1 = __builtin_bit_cast(bf16x8, h1);
  }

  float sreg[NKT][4];
  float mloc[4] = {-INFINITY, -INFINITY, -INFINITY, -INFINITY};
  float lloc[4] = {0.f, 0.f, 0.f, 0.f};

  // prefetch K tile 0 (this wave's 16 rows) + masks tile 0
  f32x4 kreg[4];
#pragma unroll
  for (int j = 0; j < 4; ++j)
    kreg[j] = kb4[(size_t)(wave * 16 + j * 4 + lrow) * 16 + (lane & 15)];
  int km_c = KM[b * SLK + wave * 16 + col];
  int msk_c[4];
#pragma unroll
  for (int r = 0; r < 4; ++r)
    msk_c[r] = MSK[mbase + (size_t)(quad * 4 + r) * SLK + wave * 16 + col];

  // =================== Pass 1 (barrier-free): S = QK^T/8, online stats ====
#pragma unroll
  for (int kt = 0; kt < NKT; ++kt) {
    // stage this wave's K rows into its private slice (same-wave ordering only)
#pragma unroll
    for (int j = 0; j < 4; ++j)
      *(u16x4*)&Kw[(j * 4 + lrow) * KSTR + lc4] = cvt4(kreg[j]);

    // prefetch tile kt+1
    int km_n = 0, msk_n[4] = {0, 0, 0, 0};
    if (kt < NKT - 1) {
      const int brow = (kt + 1) * TK + wave * 16;
#pragma unroll
      for (int j = 0; j < 4; ++j)
        kreg[j] = kb4[(size_t)(brow + j * 4 + lrow) * 16 + (lane & 15)];
      km_n = KM[b * SLK + brow + col];
#pragma unroll
      for (int r = 0; r < 4; ++r)
        msk_n[r] = MSK[mbase + (size_t)(quad * 4 + r) * SLK + brow + col];
    }

    // B-frag: K[key = wave*16+col][k = quad*8+j (+32)]
    bf16x8 bk0 = __builtin_bit_cast(bf16x8, *(const u16x8*)&Kw[col * KSTR + quad * 8]);
    bf16x8 bk1 = __builtin_bit_cast(bf16x8, *(const u16x8*)&Kw[col * KSTR + quad * 8 + 32]);
    f32x4 acc = {0.f, 0.f, 0.f, 0.f};
    acc = __builtin_amdgcn_mfma_f32_16x16x32_bf16(aq0, bk0, acc, 0, 0, 0);
    acc = __builtin_amdgcn_mfma_f32_16x16x32_bf16(aq1, bk1, acc, 0, 0, 0);

#pragma unroll
    for (int r = 0; r < 4; ++r) {
      float s = (km_c && msk_c[r]) ? acc[r] * 0.125f : -INFINITY;
      sreg[kt][r] = s;
      float mn = fmaxf(mloc[r], s);
      if (mn != -INFINITY) {
        lloc[r] = lloc[r] * __expf(mloc[r] - mn) + __expf(s - mn);
        mloc[r] = mn;
      }
    }
    km_c = km_n;
#pragma unroll
    for (int r = 0; r < 4; ++r) msk_c[r] = msk_n[r];
  }

  // prefetch V step 0 (2 tiles x this wave's 16 rows) during stats phase
  f32x4 vreg[8];
#pragma unroll
  for (int j = 0; j < 8; ++j)
    vreg[j] = vb4[(size_t)((j >> 2) * TK + wave * 16 + (j & 3) * 4 + lrow) * 16 + (lane & 15)];

  // ---- stats combine: 16-lane butterfly, then across waves (2 barriers) ----
#pragma unroll
  for (int r = 0; r < 4; ++r) {
#pragma unroll
    for (int off = 1; off < 16; off <<= 1) {
      float om = __shfl_xor(mloc[r], off, 64);
      float ol = __shfl_xor(lloc[r], off, 64);
      float mn = fmaxf(mloc[r], om);
      if (mn != -INFINITY) {
        lloc[r] = lloc[r] * __expf(mloc[r] - mn) + ol * __expf(om - mn);
        mloc[r] = mn;
      }
    }
  }
  if (col == 0) {
#pragma unroll
    for (int r = 0; r < 4; ++r) {
      partM[wave * 16 + quad * 4 + r] = mloc[r];
      partL[wave * 16 + quad * 4 + r] = lloc[r];
    }
  }
  __syncthreads();
  if (tid < TQ) {
    float M = -INFINITY, L = 0.f;
#pragma unroll
    for (int w = 0; w < 4; ++w) {
      float m_ = partM[w * 16 + tid], l_ = partL[w * 16 + tid];
      float mn = fmaxf(M, m_);
      if (mn != -INFINITY) {
        L = L * __expf(M - mn) + l_ * __expf(m_ - mn);
        M = mn;
      }
    }
    rowM[tid] = M;
    rowS[tid] = QM[b * SLQ + q0 + tid] ? (1.f / L) : 0.f;
  }
  __syncthreads();

  float Mr[4], Sr[4];
#pragma unroll
  for (int r = 0; r < 4; ++r) { Mr[r] = rowM[quad * 4 + r]; Sr[r] = rowS[quad * 4 + r]; }

  // ====== Pass 2 (barrier-free): 8 steps of 2 tiles, K=32 over private keys
  f32x4 acco[4] = {{0.f,0.f,0.f,0.f},{0.f,0.f,0.f,0.f},{0.f,0.f,0.f,0.f},{0.f,0.f,0.f,0.f}};
#pragma unroll
  for (int st = 0; st < 8; ++st) {
    const int kt0 = st * 2, kt1 = st * 2 + 1;
    // stage V rows (32: tile kt0 then kt1) into private slice
#pragma unroll
    for (int j = 0; j < 8; ++j)
      *(u16x4*)&Vw[(j * 4 + lrow) * VSTR + lc4] = cvt4(vreg[j]);

    // p for both tiles; P slice layout: row q, cols [0..15]=kt0, [16..31]=kt1
    float p0[4], p1[4];
#pragma unroll
    for (int r = 0; r < 4; ++r) {
      p0[r] = __expf(sreg[kt0][r] - Mr[r]) * Sr[r];
      p1[r] = __expf(sreg[kt1][r] - Mr[r]) * Sr[r];
      Pw[(quad * 4 + r) * PSTR + col]      = f2bf(p0[r]);
      Pw[(quad * 4 + r) * PSTR + 16 + col] = f2bf(p1[r]);
    }
#pragma unroll
    for (int r = 0; r < 4; ++r) {
      OUT_P[mbase + (size_t)(quad * 4 + r) * SLK + kt0 * TK + wave * 16 + col] = p0[r];
      OUT_P[mbase + (size_t)(quad * 4 + r) * SLK + kt1 * TK + wave * 16 + col] = p1[r];
    }

    // prefetch next step's V
    if (st < 7) {
#pragma unroll
      for (int j = 0; j < 8; ++j)
        vreg[j] = vb4[(size_t)((st * 2 + 2 + (j >> 2)) * TK + wave * 16 + (j & 3) * 4 + lrow) * 16
                      + (lane & 15)];
    }

    // A = P[q=col][vk=quad*8+j]; B = V[vk=quad*8+j][d=n0*16+col]
    bf16x8 ap = __builtin_bit_cast(bf16x8, *(const u16x8*)&Pw[col * PSTR + quad * 8]);
#pragma unroll
    for (int n0 = 0; n0 < 4; ++n0) {
      u16x8 rv;
#pragma unroll
      for (int j = 0; j < 8; ++j)
        rv[j] = Vw[(quad * 8 + j) * VSTR + n0 * 16 + col];
      acco[n0] = __builtin_amdgcn_mfma_f32_16x16x32_bf16(
          ap, __builtin_bit_cast(bf16x8, rv), acco[n0], 0, 0, 0);
    }
  }

  // ====== final O: per-wave partial -> LDS (own slot, aliases dead V) ======
#pragma unroll
  for (int n0 = 0; n0 < 4; ++n0)
#pragma unroll
    for (int r = 0; r < 4; ++r)
      Ow[(quad * 4 + r) * 64 + n0 * 16 + col] = acco[n0][r];
  __syncthreads();
  {
    const int qq = tid >> 4, dd = (tid & 15) * 4;
    f32x4 s = {0.f, 0.f, 0.f, 0.f};
#pragma unroll
    for (int w = 0; w < 4; ++w) {
      const float* Os = (const float*)(RAW + w * (32 * VSTR * 2));
      f32x4 t = *(const f32x4*)&Os[qq * 64 + dd];
      s += t;
    }
    *(f32x4*)&OUT_AV[((size_t)b * SLQ + q0 + qq) * DH + dd] = s;
  }
}

extern "C" void kernel_launch(void* const* d_in, const int* in_sizes, int n_in,
                              void* d_out, int out_size, void* d_ws, size_t ws_size,
                              hipStream_t stream) {
  const float* q  = (const float*)d_in[0];
  const float* k  = (const float*)d_in[1];
  const float* v  = (const float*)d_in[2];
  const int*   qm = (const int*)d_in[3];
  const int*   km = (const int*)d_in[4];
  const int*   mk = (const int*)d_in[5];
  float* out_av = (float*)d_out;                          // [B,LQ,D]
  float* out_p  = out_av + (size_t)NB * SLQ * DH;         // [B,LQ,LK]
  sdpa_fused<<<dim3(NB * (SLQ / TQ)), dim3(256), 0, stream>>>(q, k, v, qm, km, mk, out_av, out_p);
}